// Round 2
// baseline (666.063 us; speedup 1.0000x reference)
//
#include <hip/hip_runtime.h>
#include <hip/hip_bf16.h>
#include <stdint.h>

// ---------------------------------------------------------------------------
// SCARF embedding: X=[anchor;positive] (16384x512) -> 6x (GEMM+bias+ReLU)
// fp32-accurate via bf16x3 split MFMA (AhBh + AhBl + AlBh).
// GEMM: 128x128x64 tile, 4 waves, global_load_lds(16B), mfma_f32_16x16x32_bf16
// ---------------------------------------------------------------------------

typedef __bf16 bf16x8 __attribute__((ext_vector_type(8)));
typedef float  f32x4  __attribute__((ext_vector_type(4)));

#define BM 128
#define BN 128
#define BK 64

__device__ __forceinline__ void gload_lds16(const void* g, void* l) {
  __builtin_amdgcn_global_load_lds(
      (const __attribute__((address_space(1))) uint32_t*)g,
      (__attribute__((address_space(3))) uint32_t*)l, 16, 0, 0);
}

__device__ __forceinline__ void fsplit(float v, uint16_t& ho, uint16_t& lo) {
  __bf16 hb = (__bf16)v;                 // RNE
  float  r  = v - (float)hb;
  __bf16 lb = (__bf16)r;
  ho = __builtin_bit_cast(uint16_t, hb);
  lo = __builtin_bit_cast(uint16_t, lb);
}

// --- mask dtype detection: 1 = byte-bool, 0 = int32 ------------------------
// int32 0/1 words have bytes 1..3 == 0 always; 60%-dense byte-bools don't
// (P[all zero over 1024 words] ~ 0).
__global__ void detect_mask_kernel(const uint8_t* __restrict__ mask,
                                   int* __restrict__ flag) {
  if (threadIdx.x == 0 && blockIdx.x == 0) {
    uint32_t or_hi = 0;
    for (int i = 0; i < 1024; ++i)
      or_hi |= ((const uint32_t*)mask)[i] & 0xFFFFFF00u;
    *flag = (or_hi != 0) ? 1 : 0;
  }
}

// --- corruption + hi/lo split of [anchor; positive] ------------------------
__global__ void pack_kernel(const float* __restrict__ anchor,
                            const float* __restrict__ rnd,
                            const uint8_t* __restrict__ mask,
                            const int* __restrict__ mask_is_bytes,
                            uint16_t* __restrict__ Xhi, uint16_t* __restrict__ Xlo,
                            int total4) {
  int i = blockIdx.x * blockDim.x + threadIdx.x;
  if (i >= total4) return;
  float4 a = ((const float4*)anchor)[i];
  float4 r = ((const float4*)rnd)[i];
  const float* ap = (const float*)&a;
  const float* rp = (const float*)&r;
  uint32_t mbits;  // bit j = corruption of element 4i+j
  if (*mask_is_bytes) {
    uint32_t m = ((const uint32_t*)mask)[i];
    mbits = ((m >> 0) & 1u) | ((m >> 7) & 2u) | ((m >> 14) & 4u) | ((m >> 21) & 8u);
  } else {
    int4 mi = ((const int4*)mask)[i];
    mbits = (mi.x ? 1u : 0u) | (mi.y ? 2u : 0u) | (mi.z ? 4u : 0u) | (mi.w ? 8u : 0u);
  }
  ushort4 ah, al, ph, pl;
  uint16_t* ahp = (uint16_t*)&ah; uint16_t* alp = (uint16_t*)&al;
  uint16_t* php = (uint16_t*)&ph; uint16_t* plp = (uint16_t*)&pl;
#pragma unroll
  for (int j = 0; j < 4; ++j) {
    float av = ap[j];
    float pv = ((mbits >> j) & 1u) ? rp[j] : av;
    fsplit(av, ahp[j], alp[j]);
    fsplit(pv, php[j], plp[j]);
  }
  ((ushort4*)Xhi)[i] = ah;
  ((ushort4*)Xlo)[i] = al;
  ((ushort4*)Xhi)[i + total4] = ph;   // positive tower rows start at B*M
  ((ushort4*)Xlo)[i + total4] = pl;
}

// --- weight transpose (KxN f32 -> NxK bf16 hi/lo) --------------------------
__global__ void wprep_kernel(const float* __restrict__ W,
                             uint16_t* __restrict__ Wh, uint16_t* __restrict__ Wl,
                             int K, int N) {
  __shared__ float t[32][33];
  int k0 = blockIdx.x * 32, n0 = blockIdx.y * 32;
  int tr = threadIdx.x >> 5, tc = threadIdx.x & 31;
#pragma unroll
  for (int i = 0; i < 4; ++i)
    t[tr + i * 8][tc] = W[(size_t)(k0 + tr + i * 8) * N + n0 + tc];
  __syncthreads();
#pragma unroll
  for (int i = 0; i < 4; ++i) {
    int n = tr + i * 8;
    float v = t[tc][n];
    uint16_t h, l;
    fsplit(v, h, l);
    size_t o = (size_t)(n0 + n) * K + k0 + tc;
    Wh[o] = h; Wl[o] = l;
  }
}

// --- split-bf16 GEMM: C = relu(A @ Wt^T + bias) ----------------------------
// A: (16384 x K) bf16 hi/lo row-major; Wt: (1024 x K) bf16 hi/lo row-major.
template <int K, bool LAST>
__global__ __launch_bounds__(256, 2) void gemm_kernel(
    const uint16_t* __restrict__ Ah, const uint16_t* __restrict__ Al,
    const uint16_t* __restrict__ Bh, const uint16_t* __restrict__ Bl,
    const float* __restrict__ bias,
    uint16_t* __restrict__ Yh, uint16_t* __restrict__ Yl,
    float* __restrict__ Yf) {
  __shared__ uint16_t sAh[BM * BK], sAl[BM * BK], sBh[BN * BK], sBl[BN * BK];

  // XCD-aware swizzle: nwg=1024, bijective (1024%8==0). XCD x owns a
  // contiguous band of 16 M-tiles (A-panel L2 reuse x8, full B fits L2).
  int bid = blockIdx.x;
  int swz = (bid & 7) * 128 + (bid >> 3);
  int tn = swz & 7;         // N tile 0..7
  int tm = swz >> 3;        // M tile 0..127
  const int brow = tm * BM, bcol = tn * BN;

  const int tid = threadIdx.x;
  const int w = tid >> 6, l = tid & 63;
  const int wr = w >> 1, wc = w & 1;           // wave quadrant (64x64)
  const int lr = l >> 3, lc = (l & 7) * 8;     // staging lane offsets

  f32x4 acc[4][4];
#pragma unroll
  for (int m = 0; m < 4; ++m)
#pragma unroll
    for (int n = 0; n < 4; ++n) acc[m][n] = 0;

  for (int k0 = 0; k0 < K; k0 += BK) {
    // stage 4 tiles (Ah,Al,Bh,Bl) via async global->LDS, 16B/lane
#pragma unroll
    for (int t = 0; t < 4; ++t) {
      int r = w * 32 + t * 8;  // tile-local row chunk (8 rows = 1KB)
      size_t ga = (size_t)(brow + r + lr) * K + k0 + lc;
      size_t gb = (size_t)(bcol + r + lr) * K + k0 + lc;
      gload_lds16(Ah + ga, &sAh[r * BK]);
      gload_lds16(Al + ga, &sAl[r * BK]);
      gload_lds16(Bh + gb, &sBh[r * BK]);
      gload_lds16(Bl + gb, &sBl[r * BK]);
    }
    __syncthreads();

#pragma unroll
    for (int kk = 0; kk < 2; ++kk) {
      const int ko = kk * 32 + (l >> 4) * 8;
      bf16x8 aH[4], aL[4], bH[4], bL[4];
#pragma unroll
      for (int m = 0; m < 4; ++m) {
        int row = wr * 64 + m * 16 + (l & 15);
        aH[m] = *(const bf16x8*)&sAh[row * BK + ko];
        aL[m] = *(const bf16x8*)&sAl[row * BK + ko];
      }
#pragma unroll
      for (int n = 0; n < 4; ++n) {
        int col = wc * 64 + n * 16 + (l & 15);
        bH[n] = *(const bf16x8*)&sBh[col * BK + ko];
        bL[n] = *(const bf16x8*)&sBl[col * BK + ko];
      }
#pragma unroll
      for (int m = 0; m < 4; ++m)
#pragma unroll
        for (int n = 0; n < 4; ++n) {
          acc[m][n] = __builtin_amdgcn_mfma_f32_16x16x32_bf16(aH[m], bH[n], acc[m][n], 0, 0, 0);
          acc[m][n] = __builtin_amdgcn_mfma_f32_16x16x32_bf16(aH[m], bL[n], acc[m][n], 0, 0, 0);
          acc[m][n] = __builtin_amdgcn_mfma_f32_16x16x32_bf16(aL[m], bH[n], acc[m][n], 0, 0, 0);
        }
    }
    __syncthreads();
  }

  // epilogue: bias + relu, store bf16 hi/lo (or fp32 for last layer)
  float bb[4];
#pragma unroll
  for (int n = 0; n < 4; ++n) bb[n] = bias[bcol + wc * 64 + n * 16 + (l & 15)];
#pragma unroll
  for (int m = 0; m < 4; ++m) {
#pragma unroll
    for (int j = 0; j < 4; ++j) {
      int row = brow + wr * 64 + m * 16 + (l >> 4) * 4 + j;
#pragma unroll
      for (int n = 0; n < 4; ++n) {
        int col = bcol + wc * 64 + n * 16 + (l & 15);
        float v = acc[m][n][j] + bb[n];
        v = v > 0.f ? v : 0.f;
        size_t o = (size_t)row * 1024 + col;
        if (LAST) {
          Yf[o] = v;
        } else {
          uint16_t h, lo2;
          fsplit(v, h, lo2);
          Yh[o] = h; Yl[o] = lo2;
        }
      }
    }
  }
}

extern "C" void kernel_launch(void* const* d_in, const int* in_sizes, int n_in,
                              void* d_out, int out_size, void* d_ws, size_t ws_size,
                              hipStream_t stream) {
  (void)in_sizes; (void)n_in; (void)out_size; (void)ws_size;
  const float*   anchor = (const float*)d_in[0];
  const float*   rnd    = (const float*)d_in[1];
  const uint8_t* mask   = (const uint8_t*)d_in[2];
  const float*   enc_w0 = (const float*)d_in[3];
  const float*   enc_b0 = (const float*)d_in[4];
  const float*   enc_w  = (const float*)d_in[5];
  const float*   enc_b  = (const float*)d_in[6];
  const float*   head_w = (const float*)d_in[7];
  const float*   head_b = (const float*)d_in[8];
  float* out = (float*)d_out;

  const int B = 8192, M = 512;
  const size_t W_ELEMS = (size_t)512 * 1024 + 5ull * 1024 * 1024;  // 5,767,168

  uint16_t* WT_H = (uint16_t*)d_ws;
  uint16_t* WT_L = WT_H + W_ELEMS;
  uint16_t* X0_H = WT_L + W_ELEMS;
  uint16_t* X0_L = X0_H + (size_t)16384 * 512;
  uint16_t* Y_H  = X0_L + (size_t)16384 * 512;
  uint16_t* Y_L  = Y_H + (size_t)16384 * 1024;
  int* mflag     = (int*)(Y_L + (size_t)16384 * 1024);  // 4B past ~118MB
  // Z ping-pong buffer lives inside d_out (safe: last read is layer 4,
  // final fp32 write is layer 5)
  uint16_t* Z_H = (uint16_t*)d_out;
  uint16_t* Z_L = Z_H + (size_t)16384 * 1024;

  // 0) detect mask dtype (byte-bool vs int32), device-side, graph-safe
  detect_mask_kernel<<<1, 64, 0, stream>>>(mask, mflag);

  // 1) corruption + split
  int total4 = B * M / 4;
  pack_kernel<<<total4 / 256, 256, 0, stream>>>(anchor, rnd, mask, mflag, X0_H, X0_L, total4);

  // 2) weight transpose + split  (layer k offsets in elems)
  const size_t WOFF[6] = {0, 524288, 1572864, 2621440, 3670016, 4718592};
  wprep_kernel<<<dim3(16, 32), 256, 0, stream>>>(enc_w0, WT_H + WOFF[0], WT_L + WOFF[0], 512, 1024);
  for (int i = 0; i < 3; ++i)
    wprep_kernel<<<dim3(32, 32), 256, 0, stream>>>(enc_w + (size_t)i * 1048576,
                                                   WT_H + WOFF[1 + i], WT_L + WOFF[1 + i], 1024, 1024);
  for (int i = 0; i < 2; ++i)
    wprep_kernel<<<dim3(32, 32), 256, 0, stream>>>(head_w + (size_t)i * 1048576,
                                                   WT_H + WOFF[4 + i], WT_L + WOFF[4 + i], 1024, 1024);

  // 3) 6 fused GEMM+bias+ReLU layers
  dim3 g(1024), b(256);
  gemm_kernel<512,  false><<<g, b, 0, stream>>>(X0_H, X0_L, WT_H + WOFF[0], WT_L + WOFF[0], enc_b0,        Y_H, Y_L, nullptr);
  gemm_kernel<1024, false><<<g, b, 0, stream>>>(Y_H,  Y_L,  WT_H + WOFF[1], WT_L + WOFF[1], enc_b,         Z_H, Z_L, nullptr);
  gemm_kernel<1024, false><<<g, b, 0, stream>>>(Z_H,  Z_L,  WT_H + WOFF[2], WT_L + WOFF[2], enc_b + 1024,  Y_H, Y_L, nullptr);
  gemm_kernel<1024, false><<<g, b, 0, stream>>>(Y_H,  Y_L,  WT_H + WOFF[3], WT_L + WOFF[3], enc_b + 2048,  Z_H, Z_L, nullptr);
  gemm_kernel<1024, false><<<g, b, 0, stream>>>(Z_H,  Z_L,  WT_H + WOFF[4], WT_L + WOFF[4], head_b,        Y_H, Y_L, nullptr);
  gemm_kernel<1024, true ><<<g, b, 0, stream>>>(Y_H,  Y_L,  WT_H + WOFF[5], WT_L + WOFF[5], head_b + 1024, nullptr, nullptr, out);
}

// Round 4
// 585.969 us; speedup vs baseline: 1.1367x; 1.1367x over previous
//
#include <hip/hip_runtime.h>
#include <hip/hip_bf16.h>
#include <stdint.h>

// ---------------------------------------------------------------------------
// SCARF embedding: X=[anchor;positive] (16384x512) -> 6x (GEMM+bias+ReLU)
// fp32-accurate via bf16x3 split MFMA (AhBh + AhBl + AlBh).
// GEMM: 256x256 tile, BK=32, 8 waves, 4-phase schedule w/ raw barriers,
// late vmcnt drain, setprio, XOR-swizzled hi/lo-interleaved operand layout.
// Operand "op-layout" (produced by pack/wprep, consumed via XOR ds_read):
//   row-major rows of [K/32 groups][64 u16]; within a group, logical 16B
//   chunk l (0..3 = hi k-octets, 4..7 = lo k-octets) lives at phys slot
//   l ^ (row&7). global_load_lds copies rows linearly (swizzle preserved).
// ---------------------------------------------------------------------------

typedef __bf16 bf16x8 __attribute__((ext_vector_type(8)));
typedef float  f32x4  __attribute__((ext_vector_type(4)));
typedef unsigned short u16x8 __attribute__((ext_vector_type(8)));

__device__ __forceinline__ void gload_lds16(const void* g, void* l) {
  __builtin_amdgcn_global_load_lds(
      (const __attribute__((address_space(1))) uint32_t*)g,
      (__attribute__((address_space(3))) uint32_t*)l, 16, 0, 0);
}

__device__ __forceinline__ void fsplit(float v, uint16_t& ho, uint16_t& lo) {
  __bf16 hb = (__bf16)v;                 // RNE
  float  r  = v - (float)hb;
  __bf16 lb = (__bf16)r;
  ho = __builtin_bit_cast(uint16_t, hb);
  lo = __builtin_bit_cast(uint16_t, lb);
}

// --- mask dtype detection: 1 = byte-bool, 0 = int32 ------------------------
// int32 0/1 words have bytes 1..3 == 0 always; 60%-dense byte-bools don't
// (P[all 256 words' high bytes zero] ~ 0.4^768 ~ 0).
__global__ void detect_mask_kernel(const uint8_t* __restrict__ mask,
                                   int* __restrict__ flag) {
  if (threadIdx.x == 0 && blockIdx.x == 0) {
    uint32_t or_hi = 0;
    for (int i = 0; i < 256; ++i)
      or_hi |= ((const uint32_t*)mask)[i] & 0xFFFFFF00u;
    *flag = (or_hi != 0) ? 1 : 0;
  }
}

// --- corruption + split + op-layout pack -----------------------------------
// thread t: row = t>>6 (0..8191), idx = t&63 -> 8 k's; writes anchor row and
// positive row (+8192) in op-layout.
__global__ void pack_kernel(const float* __restrict__ anchor,
                            const float* __restrict__ rnd,
                            const uint8_t* __restrict__ mask,
                            const int* __restrict__ mask_is_bytes,
                            uint16_t* __restrict__ Xop) {
  int t = blockIdx.x * 256 + threadIdx.x;    // 524288 threads
  int row = t >> 6;
  int idx = t & 63;
  int g = idx >> 2, c = idx & 3;
  int kbase = idx * 8;
  const float4* ap = (const float4*)(anchor + (size_t)row * 512 + kbase);
  const float4* rp = (const float4*)(rnd + (size_t)row * 512 + kbase);
  float a[8], r[8];
  *(float4*)&a[0] = ap[0]; *(float4*)&a[4] = ap[1];
  *(float4*)&r[0] = rp[0]; *(float4*)&r[4] = rp[1];
  uint32_t mb;
  if (*mask_is_bytes) {
    const uint32_t* mp = (const uint32_t*)(mask + (size_t)row * 512 + kbase);
    uint32_t w0 = mp[0], w1 = mp[1];
    mb = 0;
#pragma unroll
    for (int j = 0; j < 4; ++j) {
      mb |= ((w0 >> (8 * j)) & 1u) << j;
      mb |= ((w1 >> (8 * j)) & 1u) << (4 + j);
    }
  } else {
    const int* mi = (const int*)mask + (size_t)row * 512 + kbase;
    int4 m0 = ((const int4*)mi)[0], m1 = ((const int4*)mi)[1];
    mb = (m0.x ? 1u : 0) | (m0.y ? 2u : 0) | (m0.z ? 4u : 0) | (m0.w ? 8u : 0) |
         (m1.x ? 16u : 0) | (m1.y ? 32u : 0) | (m1.z ? 64u : 0) | (m1.w ? 128u : 0);
  }
  u16x8 ah, al, ph, pl;
#pragma unroll
  for (int j = 0; j < 8; ++j) {
    uint16_t h, lo;
    fsplit(a[j], h, lo); ah[j] = h; al[j] = lo;
    float pv = ((mb >> j) & 1u) ? r[j] : a[j];
    fsplit(pv, h, lo); ph[j] = h; pl[j] = lo;
  }
  int s = row & 7;                         // (row+8192)&7 == row&7
  size_t base = ((size_t)row * 16 + g) * 64;
  *(u16x8*)(Xop + base + (size_t)((c ^ s)) * 8) = ah;
  *(u16x8*)(Xop + base + (size_t)(((c + 4) ^ s)) * 8) = al;
  size_t pbase = ((size_t)(row + 8192) * 16 + g) * 64;
  *(u16x8*)(Xop + pbase + (size_t)((c ^ s)) * 8) = ph;
  *(u16x8*)(Xop + pbase + (size_t)(((c + 4) ^ s)) * 8) = pl;
}

// --- weight prep: W (Kx1024 f32) -> op-layout NxK hi/lo --------------------
__global__ void wprep_kernel(const float* __restrict__ W,
                             uint16_t* __restrict__ Bop, int K) {
  __shared__ float tbuf[32][33];
  int g = blockIdx.x, n0 = blockIdx.y * 32;
  int tid = threadIdx.x;
#pragma unroll
  for (int i = 0; i < 4; ++i)
    tbuf[(tid >> 5) + i * 8][tid & 31] =
        W[((size_t)g * 32 + (tid >> 5) + i * 8) * 1024 + n0 + (tid & 31)];
  __syncthreads();
  if (tid < 128) {
    int nl = tid >> 2, c = tid & 3;
    int n = n0 + nl, s = n & 7;
    u16x8 hi, lo;
#pragma unroll
    for (int j = 0; j < 8; ++j) {
      uint16_t h, l2;
      fsplit(tbuf[c * 8 + j][nl], h, l2);
      hi[j] = h; lo[j] = l2;
    }
    size_t base = ((size_t)n * (K / 32) + g) * 64;
    *(u16x8*)(Bop + base + (size_t)((c ^ s)) * 8) = hi;
    *(u16x8*)(Bop + base + (size_t)(((c + 4) ^ s)) * 8) = lo;
  }
}

// --- 4-phase split-bf16 GEMM: C = relu(A @ W^T + bias) ---------------------
__device__ __forceinline__ void mfma_row(f32x4* accrow, bf16x8 aH, bf16x8 aL,
                                         const bf16x8* bh, const bf16x8* bl) {
#pragma unroll
  for (int n = 0; n < 4; ++n) {
    accrow[n] = __builtin_amdgcn_mfma_f32_16x16x32_bf16(aH, bh[n], accrow[n], 0, 0, 0);
    accrow[n] = __builtin_amdgcn_mfma_f32_16x16x32_bf16(aH, bl[n], accrow[n], 0, 0, 0);
    accrow[n] = __builtin_amdgcn_mfma_f32_16x16x32_bf16(aL, bh[n], accrow[n], 0, 0, 0);
  }
}

template <int K, bool LAST>
__global__ __launch_bounds__(512, 2) void gemm_kernel(
    const uint16_t* __restrict__ Aop, const uint16_t* __restrict__ Bop,
    const float* __restrict__ bias,
    uint16_t* __restrict__ Yop, float* __restrict__ Yf) {
  constexpr int KG = K / 32;
  __shared__ uint16_t sA[2][256 * 64];
  __shared__ uint16_t sB[2][256 * 64];

  // XCD-chunked swizzle: 256 blocks, xcd = bid&7 owns 8 M-tiles x 4 N-tiles
  int bid = blockIdx.x;
  int xcd = bid & 7, lid = bid >> 3;
  int tm = xcd * 8 + (lid >> 2), tn = lid & 3;
  const int brow = tm * 256, bcol = tn * 256;

  const int tid = threadIdx.x;
  const int l = tid & 63, w = tid >> 6;
  const int wr = w >> 2, wc = w & 3;       // 2x4 wave grid; per-wave C 128x64
  const int l15 = l & 15, c16 = l >> 4;    // frag col/row + k-chunk

  f32x4 acc[8][4];
#pragma unroll
  for (int m = 0; m < 8; ++m)
#pragma unroll
    for (int n = 0; n < 4; ++n) acc[m][n] = 0;

#define STAGE_A(g_, buf_)                                                     \
  _Pragma("unroll") for (int i = 0; i < 4; ++i) {                             \
    int row_ = i * 64 + (tid >> 3);                                           \
    gload_lds16(Aop + ((size_t)(brow + row_) * KG + (g_)) * 64 + (tid & 7) * 8,\
                &sA[buf_][i * 4096 + tid * 8]);                               \
  }
#define STAGE_B(g_, buf_)                                                     \
  _Pragma("unroll") for (int i = 0; i < 4; ++i) {                             \
    int row_ = i * 64 + (tid >> 3);                                           \
    gload_lds16(Bop + ((size_t)(bcol + row_) * KG + (g_)) * 64 + (tid & 7) * 8,\
                &sB[buf_][i * 4096 + tid * 8]);                               \
  }
#define READ_A(mm, aH, aL)                                                    \
  {                                                                           \
    int fr_ = wr * 128 + (mm)*16 + l15;                                       \
    const uint16_t* rp_ = pA + fr_ * 64;                                      \
    aH = *(const bf16x8*)(rp_ + ((c16 ^ (fr_ & 7))) * 8);                     \
    aL = *(const bf16x8*)(rp_ + (((c16 + 4) ^ (fr_ & 7))) * 8);               \
  }
#define BARRIER() __builtin_amdgcn_s_barrier()
#define LGKM0()                                                               \
  asm volatile("s_waitcnt lgkmcnt(0)" ::: "memory");                          \
  __builtin_amdgcn_sched_barrier(0)
#define VM0()                                                                 \
  asm volatile("s_waitcnt vmcnt(0)" ::: "memory");                            \
  __builtin_amdgcn_sched_barrier(0)

  // prologue: stage tile 0
  STAGE_A(0, 0)
  STAGE_B(0, 0)
  VM0();
  BARRIER();

  int cur = 0;
#pragma unroll 1
  for (int g = 0; g < KG; ++g) {
    const uint16_t* pA = &sA[cur][0];
    const uint16_t* pB = &sB[cur][0];
    const bool pf = (g + 1 < KG);
    const int nxt = cur ^ 1;

    // ---- P0: B frags (8 reads) + A m0,m1 (4 reads); issue A prefetch
    bf16x8 bh[4], bl[4];
#pragma unroll
    for (int n = 0; n < 4; ++n) {
      int fc = wc * 64 + n * 16 + l15;
      const uint16_t* rp = pB + fc * 64;
      bh[n] = *(const bf16x8*)(rp + ((c16 ^ (fc & 7))) * 8);
      bl[n] = *(const bf16x8*)(rp + (((c16 + 4) ^ (fc & 7))) * 8);
    }
    bf16x8 a0h, a0l, a1h, a1l;
    READ_A(0, a0h, a0l)
    READ_A(1, a1h, a1l)
    if (pf) { STAGE_A(g + 1, nxt) }
    BARRIER();
    LGKM0();
    __builtin_amdgcn_s_setprio(1);
    mfma_row(acc[0], a0h, a0l, bh, bl);
    mfma_row(acc[1], a1h, a1l, bh, bl);
    __builtin_amdgcn_s_setprio(0);
    BARRIER();

    // ---- P1: A m2,m3; issue B prefetch
    bf16x8 a2h, a2l, a3h, a3l;
    READ_A(2, a2h, a2l)
    READ_A(3, a3h, a3l)
    if (pf) { STAGE_B(g + 1, nxt) }
    BARRIER();
    LGKM0();
    __builtin_amdgcn_s_setprio(1);
    mfma_row(acc[2], a2h, a2l, bh, bl);
    mfma_row(acc[3], a3h, a3l, bh, bl);
    __builtin_amdgcn_s_setprio(0);
    BARRIER();

    // ---- P2: A m4,m5
    bf16x8 a4h, a4l, a5h, a5l;
    READ_A(4, a4h, a4l)
    READ_A(5, a5h, a5l)
    BARRIER();
    LGKM0();
    __builtin_amdgcn_s_setprio(1);
    mfma_row(acc[4], a4h, a4l, bh, bl);
    mfma_row(acc[5], a5h, a5l, bh, bl);
    __builtin_amdgcn_s_setprio(0);
    BARRIER();

    // ---- P3: A m6,m7; drain prefetch (issued 2-3 phases ago) then flip
    bf16x8 a6h, a6l, a7h, a7l;
    READ_A(6, a6h, a6l)
    READ_A(7, a7h, a7l)
    BARRIER();
    LGKM0();
    __builtin_amdgcn_s_setprio(1);
    mfma_row(acc[6], a6h, a6l, bh, bl);
    mfma_row(acc[7], a7h, a7l, bh, bl);
    __builtin_amdgcn_s_setprio(0);
    VM0();
    BARRIER();
    cur = nxt;
  }

  // ---- epilogue: bias + relu; store op-layout bf16 hi/lo (or fp32 last)
  float bb[4];
  int colg[4], colc[4], cole[4];
#pragma unroll
  for (int n = 0; n < 4; ++n) {
    int col = bcol + wc * 64 + n * 16 + l15;
    bb[n] = bias[col];
    colg[n] = col >> 5; colc[n] = (col >> 3) & 3; cole[n] = col & 7;
  }
#pragma unroll
  for (int m = 0; m < 8; ++m) {
#pragma unroll
    for (int j = 0; j < 4; ++j) {
      int rowY = brow + wr * 128 + m * 16 + c16 * 4 + j;  // C/D: row=(l>>4)*4+j
      int s = rowY & 7;
#pragma unroll
      for (int n = 0; n < 4; ++n) {
        float v = acc[m][n][j] + bb[n];
        v = v > 0.f ? v : 0.f;
        if (LAST) {
          Yf[(size_t)rowY * 1024 + bcol + wc * 64 + n * 16 + l15] = v;
        } else {
          uint16_t h, lo2;
          fsplit(v, h, lo2);
          size_t base = ((size_t)rowY * 32 + colg[n]) * 64;
          Yop[base + (size_t)((colc[n] ^ s)) * 8 + cole[n]] = h;
          Yop[base + (size_t)(((colc[n] + 4) ^ s)) * 8 + cole[n]] = lo2;
        }
      }
    }
  }
#undef STAGE_A
#undef STAGE_B
#undef READ_A
#undef BARRIER
#undef LGKM0
#undef VM0
}

extern "C" void kernel_launch(void* const* d_in, const int* in_sizes, int n_in,
                              void* d_out, int out_size, void* d_ws, size_t ws_size,
                              hipStream_t stream) {
  (void)in_sizes; (void)n_in; (void)out_size; (void)ws_size;
  const float*   anchor = (const float*)d_in[0];
  const float*   rnd    = (const float*)d_in[1];
  const uint8_t* mask   = (const uint8_t*)d_in[2];
  const float*   enc_w0 = (const float*)d_in[3];
  const float*   enc_b0 = (const float*)d_in[4];
  const float*   enc_w  = (const float*)d_in[5];
  const float*   enc_b  = (const float*)d_in[6];
  const float*   head_w = (const float*)d_in[7];
  const float*   head_b = (const float*)d_in[8];
  float* out = (float*)d_out;

  // op-layout sizes (u16 elems): W layer = 1024*(K/32)*64 = K*2048
  const size_t WSZ0 = (size_t)512 * 2048;        // 1,048,576
  const size_t WSZ1 = (size_t)1024 * 2048;       // 2,097,152
  uint16_t* Wop = (uint16_t*)d_ws;               // 6 layers: 23 MB
  size_t WOFF[6];
  WOFF[0] = 0;
  WOFF[1] = WSZ0;
  for (int i = 2; i < 6; ++i) WOFF[i] = WOFF[i - 1] + WSZ1;
  uint16_t* Xop = Wop + WOFF[5] + WSZ1;          // 16384*1024 u16 = 32 MB
  uint16_t* Yop = Xop + (size_t)16384 * 1024;    // 16384*2048 u16 = 64 MB
  int* mflag = (int*)(Yop + (size_t)16384 * 2048);
  // Z ping-pong inside d_out (64 MB exactly); dead before final fp32 write
  uint16_t* Zop = (uint16_t*)d_out;

  // 0) mask dtype detection (graph-safe, recomputed every launch)
  detect_mask_kernel<<<1, 64, 0, stream>>>(mask, mflag);

  // 1) corruption + split + op-layout pack
  pack_kernel<<<2048, 256, 0, stream>>>(anchor, rnd, mask, mflag, Xop);

  // 2) weight prep
  wprep_kernel<<<dim3(16, 32), 256, 0, stream>>>(enc_w0, Wop + WOFF[0], 512);
  for (int i = 0; i < 3; ++i)
    wprep_kernel<<<dim3(32, 32), 256, 0, stream>>>(enc_w + (size_t)i * 1048576,
                                                   Wop + WOFF[1 + i], 1024);
  for (int i = 0; i < 2; ++i)
    wprep_kernel<<<dim3(32, 32), 256, 0, stream>>>(head_w + (size_t)i * 1048576,
                                                   Wop + WOFF[4 + i], 1024);

  // 3) 6 fused GEMM+bias+ReLU layers (256 blocks = 1/CU)
  dim3 g(256), b(512);
  gemm_kernel<512,  false><<<g, b, 0, stream>>>(Xop, Wop + WOFF[0], enc_b0,        Yop, nullptr);
  gemm_kernel<1024, false><<<g, b, 0, stream>>>(Yop, Wop + WOFF[1], enc_b,         Zop, nullptr);
  gemm_kernel<1024, false><<<g, b, 0, stream>>>(Zop, Wop + WOFF[2], enc_b + 1024,  Yop, nullptr);
  gemm_kernel<1024, false><<<g, b, 0, stream>>>(Yop, Wop + WOFF[3], enc_b + 2048,  Zop, nullptr);
  gemm_kernel<1024, false><<<g, b, 0, stream>>>(Zop, Wop + WOFF[4], head_b,        Yop, nullptr);
  gemm_kernel<1024, true ><<<g, b, 0, stream>>>(Yop, Wop + WOFF[5], head_b + 1024, nullptr, out);
}